// Round 13
// baseline (227.483 us; speedup 1.0000x reference)
//
#include <hip/hip_runtime.h>
#include <hip/hip_bf16.h>
#include <stdint.h>

typedef __attribute__((ext_vector_type(4))) float f32x4;
typedef __attribute__((ext_vector_type(8))) short bf16x8;
typedef __attribute__((ext_vector_type(4))) int i32x4;

constexpr int SDIM = 2048;
constexpr int ODIM = 4096;
constexpr int INTD = 3840;
constexpr int FPD  = 256;

// RNE float->bf16
__device__ __forceinline__ unsigned short f2bf(float f) {
  union { float f; unsigned u; } a; a.f = f;
  unsigned r = a.u + 0x7fffu + ((a.u >> 16) & 1u);
  return (unsigned short)(r >> 16);
}

__device__ __forceinline__ void gload16(const void* g, void* l) {
  __builtin_amdgcn_global_load_lds(
      (const __attribute__((address_space(1))) void*)g,
      (__attribute__((address_space(3))) void*)l, 16, 0, 0);
}

// ---------------------------------------------------------------------------
// Fused prep (unchanged): blocks [0,2048) -> x rows, rest -> w rows.
// ---------------------------------------------------------------------------
__global__ __launch_bounds__(256) void prep_kernel(
    const float* __restrict__ x,
    const float* __restrict__ iw,
    const float* __restrict__ fw,
    const int* __restrict__ int_idx,
    const int* __restrict__ fp_idx,
    unsigned* __restrict__ A8,
    unsigned short* __restrict__ Afp,
    unsigned* __restrict__ W8,
    unsigned short* __restrict__ Wfp,
    float* __restrict__ qs)
{
  const int t = threadIdx.x;
  if (blockIdx.x >= SDIM) {
    const int o = blockIdx.x - SDIM;
    const f32x4* iwr = (const f32x4*)(iw + (size_t)o * INTD);
    unsigned* Wr = W8 + (size_t)o * 960;
    #pragma unroll
    for (int i = 0; i < 4; ++i) {
      const int g = t + (i << 8);
      if (g < 960) {
        f32x4 v = __builtin_nontemporal_load(iwr + g);
        int q0 = __float2int_rn(v[0]), q1 = __float2int_rn(v[1]);
        int q2 = __float2int_rn(v[2]), q3 = __float2int_rn(v[3]);
        Wr[g] = (unsigned)(q0 & 255) | ((unsigned)(q1 & 255) << 8) |
                ((unsigned)(q2 & 255) << 16) | ((unsigned)(q3 & 255) << 24);
      }
    }
    const float fwv = __builtin_nontemporal_load(fw + (size_t)o * FPD + t);
    Wfp[(size_t)o * FPD + t] = f2bf(fwv);
    return;
  }

  __shared__ float row[4096];
  __shared__ float red[4];
  const int s = blockIdx.x;
  const f32x4* xr = (const f32x4*)(x + (size_t)s * 4096);
  #pragma unroll
  for (int i = 0; i < 4; ++i)
    ((f32x4*)row)[t + 256 * i] = __builtin_nontemporal_load(xr + t + 256 * i);
  __syncthreads();

  float vals[16];
  float m = 0.f;
  #pragma unroll
  for (int i = 0; i < 4; ++i) {
    const int g = t + (i << 8);
    if (g < 960) {
      int4 idx = ((const int4*)int_idx)[g];
      float v0 = row[idx.x], v1 = row[idx.y], v2 = row[idx.z], v3 = row[idx.w];
      vals[i*4+0] = v0; vals[i*4+1] = v1; vals[i*4+2] = v2; vals[i*4+3] = v3;
      m = fmaxf(m, fmaxf(fmaxf(fabsf(v0), fabsf(v1)), fmaxf(fabsf(v2), fabsf(v3))));
    }
  }
  #pragma unroll
  for (int off = 32; off; off >>= 1)
    m = fmaxf(m, __shfl_xor(m, off));
  if ((t & 63) == 0) red[t >> 6] = m;
  __syncthreads();
  const float mx = fmaxf(fmaxf(red[0], red[1]), fmaxf(red[2], red[3]));
  if (t == 0) qs[s] = mx / 127.0f;        // exactly as reference: max/QMAX
  const float rcp = 127.0f / mx;

  unsigned* Ar = A8 + (size_t)s * 960;
  #pragma unroll
  for (int i = 0; i < 4; ++i) {
    const int g = t + (i << 8);
    if (g < 960) {
      unsigned pk = 0;
      #pragma unroll
      for (int e = 0; e < 4; ++e) {
        float q = rintf(vals[i*4+e] * rcp);
        q = fminf(fmaxf(q, -128.f), 127.f);
        pk |= ((unsigned)((int)q & 255)) << (e * 8);
      }
      Ar[g] = pk;
    }
  }
  Afp[(size_t)s * FPD + t] = f2bf(row[fp_idx[t]]);
}

// ---------------------------------------------------------------------------
// GEMM: 2-phase skeleton, 16x16 MFMAs, BK=64 B -> LDS 32 KiB/block ->
// 5 blocks/CU (was 2).  Mechanism (m114): resident blocks at different
// phases hide each other's barrier drain; occupancy was the binding
// constraint (r10: 17% occ, nothing saturated).
// Swizzle: phys_chunk = c ^ (row&3) ^ ((row>>2)&3)  (4-chunk domain,
// uniform 8-lanes-per-bank-group by enumeration), both sides (rule #21).
// ---------------------------------------------------------------------------
__global__ __launch_bounds__(256, 5) void gemm_kernel(
    const char* __restrict__ A8,    // SDIM x 3840 (i8)
    const char* __restrict__ W8,    // ODIM x 3840 (i8)
    const char* __restrict__ Afp,   // SDIM x 512 B (bf16)
    const char* __restrict__ Wfp,   // ODIM x 512 B (bf16)
    const float* __restrict__ qs,
    const float* __restrict__ wsc,
    const float* __restrict__ bias,
    float* __restrict__ out)        // SDIM x ODIM f32
{
  __shared__ char lds[2][2][128][64];   // 32 KiB
  const int tid  = threadIdx.x;
  const int lane = tid & 63;
  const int wid  = tid >> 6;
  const int wr   = wid >> 1, wc = wid & 1;

  const int bid = blockIdx.x;
  const int swz = (bid & 7) * 64 + (bid >> 3);   // 512 % 8 == 0 -> bijective
  const int srow0 = (swz & 15) * 128;
  const int ocol0 = (swz >> 4) * 128;

  // Read offsets: frag row spans 16; chunk c = lane>>4 covers the 64 B row.
  int aoff[4], boff[4];
  const int c = lane >> 4;
  #pragma unroll
  for (int i = 0; i < 4; ++i) {
    const int rowA = wr * 64 + i * 16 + (lane & 15);
    const int rowB = wc * 64 + i * 16 + (lane & 15);
    const int fA = (rowA & 3) ^ ((rowA >> 2) & 3);
    const int fB = (rowB & 3) ^ ((rowB >> 2) & 3);
    aoff[i] = rowA * 64 + ((c ^ fA) * 16);
    boff[i] = rowB * 64 + ((c ^ fB) * 16);
  }

  // Staging: per wave-load, 64 lanes cover 16 rows x 4 chunks (1024 B).
  // LDS dest is linear (base + lane*16); global source chunk pre-swizzled.
  auto stage8 = [&](int ktB, int buf) {
    #pragma unroll
    for (int q = 0; q < 2; ++q) {
      const int rb = wid * 32 + q * 16;
      const int rl = rb + (lane >> 2);
      const int cl = (lane & 3) ^ (rl & 3) ^ ((rl >> 2) & 3);
      gload16(A8 + (size_t)(srow0 + rl) * INTD + ktB + cl * 16,
              &lds[buf][0][rb][0]);
      gload16(W8 + (size_t)(ocol0 + rl) * INTD + ktB + cl * 16,
              &lds[buf][1][rb][0]);
    }
  };
  auto stagefp = [&](int ktB, int buf) {
    #pragma unroll
    for (int q = 0; q < 2; ++q) {
      const int rb = wid * 32 + q * 16;
      const int rl = rb + (lane >> 2);
      const int cl = (lane & 3) ^ (rl & 3) ^ ((rl >> 2) & 3);
      gload16(Afp + (size_t)(srow0 + rl) * 512 + ktB + cl * 16,
              &lds[buf][0][rb][0]);
      gload16(Wfp + (size_t)(ocol0 + rl) * 512 + ktB + cl * 16,
              &lds[buf][1][rb][0]);
    }
  };

  i32x4 iacc[4][4];
  #pragma unroll
  for (int i = 0; i < 4; ++i)
    #pragma unroll
    for (int j = 0; j < 4; ++j)
      iacc[i][j] = i32x4{0, 0, 0, 0};

  stage8(0, 0);
  int cur = 0;
  constexpr int NT8 = INTD / 64;   // 60
  for (int t = 0; t < NT8; ++t) {
    __syncthreads();
    if (t + 1 < NT8) stage8((t + 1) * 64, cur ^ 1);
    else             stagefp(0, cur ^ 1);
    const char* Al = &lds[cur][0][0][0];
    const char* Bl = &lds[cur][1][0][0];
    i32x4 af[4], bv[4];
    #pragma unroll
    for (int i = 0; i < 4; ++i) af[i] = *(const i32x4*)(Al + aoff[i]);
    #pragma unroll
    for (int j = 0; j < 4; ++j) bv[j] = *(const i32x4*)(Bl + boff[j]);
    #pragma unroll
    for (int i = 0; i < 4; ++i)
      #pragma unroll
      for (int j = 0; j < 4; ++j)
        iacc[i][j] = __builtin_amdgcn_mfma_i32_16x16x64_i8(
            af[i], bv[j], iacc[i][j], 0, 0, 0);
    cur ^= 1;
  }

  const int r4 = (lane >> 4) * 4;
  const int cn = lane & 15;
  float wo[4], qv[4][4];
  #pragma unroll
  for (int j = 0; j < 4; ++j) wo[j] = wsc[ocol0 + wc * 64 + j * 16 + cn];
  #pragma unroll
  for (int i = 0; i < 4; ++i)
    #pragma unroll
    for (int r = 0; r < 4; ++r)
      qv[i][r] = qs[srow0 + wr * 64 + i * 16 + r4 + r];

  f32x4 facc[4][4];
  #pragma unroll
  for (int i = 0; i < 4; ++i)
    #pragma unroll
    for (int j = 0; j < 4; ++j)
      #pragma unroll
      for (int r = 0; r < 4; ++r)
        facc[i][j][r] = (float)iacc[i][j][r] * wo[j] * qv[i][r];

  constexpr int NTF = (FPD * 2) / 64;   // 8
  for (int t = 0; t < NTF; ++t) {
    __syncthreads();
    if (t + 1 < NTF) stagefp((t + 1) * 64, cur ^ 1);
    const char* Al = &lds[cur][0][0][0];
    const char* Bl = &lds[cur][1][0][0];
    bf16x8 af[4], bv[4];
    #pragma unroll
    for (int i = 0; i < 4; ++i) af[i] = *(const bf16x8*)(Al + aoff[i]);
    #pragma unroll
    for (int j = 0; j < 4; ++j) bv[j] = *(const bf16x8*)(Bl + boff[j]);
    #pragma unroll
    for (int i = 0; i < 4; ++i)
      #pragma unroll
      for (int j = 0; j < 4; ++j)
        facc[i][j] = __builtin_amdgcn_mfma_f32_16x16x32_bf16(
            af[i], bv[j], facc[i][j], 0, 0, 0);
    cur ^= 1;
  }

  #pragma unroll
  for (int j = 0; j < 4; ++j) {
    const int o  = ocol0 + wc * 64 + j * 16 + cn;
    const float bo = bias[o];
    #pragma unroll
    for (int i = 0; i < 4; ++i) {
      const int sbase = srow0 + wr * 64 + i * 16 + r4;
      #pragma unroll
      for (int r = 0; r < 4; ++r)
        out[(size_t)(sbase + r) * ODIM + o] = facc[i][j][r] + bo;
    }
  }
}

// ---------------------------------------------------------------------------
extern "C" void kernel_launch(void* const* d_in, const int* in_sizes, int n_in,
                              void* d_out, int out_size, void* d_ws, size_t ws_size,
                              hipStream_t stream) {
  const float* x    = (const float*)d_in[0];
  const float* iw   = (const float*)d_in[1];
  const float* fw   = (const float*)d_in[2];
  const float* wsc  = (const float*)d_in[3];
  const float* bias = (const float*)d_in[4];
  const int* int_idx = (const int*)d_in[5];
  const int* fp_idx  = (const int*)d_in[6];
  float* out = (float*)d_out;

  char* ws = (char*)d_ws;
  char* A8  = ws;                                   // 2048*3840  = 7.86 MB
  char* W8  = A8 + (size_t)SDIM * INTD;             // 4096*3840  = 15.7 MB
  char* Afp = W8 + (size_t)ODIM * INTD;             // 2048*256*2 = 1.0 MB
  char* Wfp = Afp + (size_t)SDIM * FPD * 2;         // 4096*256*2 = 2.1 MB
  float* qs = (float*)(Wfp + (size_t)ODIM * FPD * 2);

  prep_kernel<<<SDIM + ODIM, 256, 0, stream>>>(x, iw, fw, int_idx, fp_idx,
                                               (unsigned*)A8, (unsigned short*)Afp,
                                               (unsigned*)W8, (unsigned short*)Wfp, qs);
  gemm_kernel<<<512, 256, 0, stream>>>(A8, W8, Afp, Wfp, qs, wsc, bias, out);
}

// Round 14
// 175.014 us; speedup vs baseline: 1.2998x; 1.2998x over previous
//
#include <hip/hip_runtime.h>
#include <hip/hip_bf16.h>
#include <stdint.h>

typedef __attribute__((ext_vector_type(4))) float f32x4;
typedef __attribute__((ext_vector_type(16))) float f32x16;
typedef __attribute__((ext_vector_type(8))) short bf16x8;
typedef __attribute__((ext_vector_type(4))) int i32x4;
typedef __attribute__((ext_vector_type(16))) int i32x16;

constexpr int SDIM = 2048;
constexpr int ODIM = 4096;
constexpr int INTD = 3840;
constexpr int FPD  = 256;

// RNE float->bf16
__device__ __forceinline__ unsigned short f2bf(float f) {
  union { float f; unsigned u; } a; a.f = f;
  unsigned r = a.u + 0x7fffu + ((a.u >> 16) & 1u);
  return (unsigned short)(r >> 16);
}

__device__ __forceinline__ void gload16(const void* g, void* l) {
  __builtin_amdgcn_global_load_lds(
      (const __attribute__((address_space(1))) void*)g,
      (__attribute__((address_space(3))) void*)l, 16, 0, 0);
}

// ---------------------------------------------------------------------------
// Fused prep: blocks [0,2048) -> x rows, rest -> w rows.
// ---------------------------------------------------------------------------
__global__ __launch_bounds__(256) void prep_kernel(
    const float* __restrict__ x,
    const float* __restrict__ iw,
    const float* __restrict__ fw,
    const int* __restrict__ int_idx,
    const int* __restrict__ fp_idx,
    unsigned* __restrict__ A8,
    unsigned short* __restrict__ Afp,
    unsigned* __restrict__ W8,
    unsigned short* __restrict__ Wfp,
    float* __restrict__ qs)
{
  const int t = threadIdx.x;
  if (blockIdx.x >= SDIM) {
    const int o = blockIdx.x - SDIM;
    const f32x4* iwr = (const f32x4*)(iw + (size_t)o * INTD);
    unsigned* Wr = W8 + (size_t)o * 960;
    #pragma unroll
    for (int i = 0; i < 4; ++i) {
      const int g = t + (i << 8);
      if (g < 960) {
        f32x4 v = __builtin_nontemporal_load(iwr + g);
        int q0 = __float2int_rn(v[0]), q1 = __float2int_rn(v[1]);
        int q2 = __float2int_rn(v[2]), q3 = __float2int_rn(v[3]);
        Wr[g] = (unsigned)(q0 & 255) | ((unsigned)(q1 & 255) << 8) |
                ((unsigned)(q2 & 255) << 16) | ((unsigned)(q3 & 255) << 24);
      }
    }
    const float fwv = __builtin_nontemporal_load(fw + (size_t)o * FPD + t);
    Wfp[(size_t)o * FPD + t] = f2bf(fwv);
    return;
  }

  __shared__ float row[4096];
  __shared__ float red[4];
  const int s = blockIdx.x;
  const f32x4* xr = (const f32x4*)(x + (size_t)s * 4096);
  #pragma unroll
  for (int i = 0; i < 4; ++i)
    ((f32x4*)row)[t + 256 * i] = __builtin_nontemporal_load(xr + t + 256 * i);
  __syncthreads();

  float vals[16];
  float m = 0.f;
  #pragma unroll
  for (int i = 0; i < 4; ++i) {
    const int g = t + (i << 8);
    if (g < 960) {
      int4 idx = ((const int4*)int_idx)[g];
      float v0 = row[idx.x], v1 = row[idx.y], v2 = row[idx.z], v3 = row[idx.w];
      vals[i*4+0] = v0; vals[i*4+1] = v1; vals[i*4+2] = v2; vals[i*4+3] = v3;
      m = fmaxf(m, fmaxf(fmaxf(fabsf(v0), fabsf(v1)), fmaxf(fabsf(v2), fabsf(v3))));
    }
  }
  #pragma unroll
  for (int off = 32; off; off >>= 1)
    m = fmaxf(m, __shfl_xor(m, off));
  if ((t & 63) == 0) red[t >> 6] = m;
  __syncthreads();
  const float mx = fmaxf(fmaxf(red[0], red[1]), fmaxf(red[2], red[3]));
  if (t == 0) qs[s] = mx / 127.0f;        // exactly as reference: max/QMAX
  const float rcp = 127.0f / mx;

  unsigned* Ar = A8 + (size_t)s * 960;
  #pragma unroll
  for (int i = 0; i < 4; ++i) {
    const int g = t + (i << 8);
    if (g < 960) {
      unsigned pk = 0;
      #pragma unroll
      for (int e = 0; e < 4; ++e) {
        float q = rintf(vals[i*4+e] * rcp);
        q = fminf(fmaxf(q, -128.f), 127.f);
        pk |= ((unsigned)((int)q & 255)) << (e * 8);
      }
      Ar[g] = pk;
    }
  }
  Afp[(size_t)s * FPD + t] = f2bf(row[fp_idx[t]]);
}

// ---------------------------------------------------------------------------
// GEMM (r10-validated best): 2-phase skeleton, 32x32 MFMAs, BK=128 B,
// XOR swizzle f(row) = (row&7) ^ ((row>>3)&3) both sides (rule #21).
// Measured: 44.8 us, SQ_LDS_BANK_CONFLICT = 0.
// ---------------------------------------------------------------------------
__global__ __launch_bounds__(256, 2) void gemm_kernel(
    const char* __restrict__ A8,    // SDIM x 3840 (i8)
    const char* __restrict__ W8,    // ODIM x 3840 (i8)
    const char* __restrict__ Afp,   // SDIM x 512 B (bf16)
    const char* __restrict__ Wfp,   // ODIM x 512 B (bf16)
    const float* __restrict__ qs,
    const float* __restrict__ wsc,
    const float* __restrict__ bias,
    float* __restrict__ out)        // SDIM x ODIM f32
{
  __shared__ char lds[2][2][128][128];   // 64 KiB
  const int tid  = threadIdx.x;
  const int lane = tid & 63;
  const int wid  = tid >> 6;
  const int wr   = wid >> 1, wc = wid & 1;
  const int h    = lane >> 5;            // k-half select for 32x32 fragments
  const int l31  = lane & 31;

  const int bid = blockIdx.x;
  const int swz = (bid & 7) * 64 + (bid >> 3);   // 512 % 8 == 0 -> bijective
  const int srow0 = (swz & 15) * 128;
  const int ocol0 = (swz >> 4) * 128;

  // Scale hoists.
  float wo[2], bo[2];
  #pragma unroll
  for (int bj = 0; bj < 2; ++bj) {
    wo[bj] = wsc[ocol0 + wc * 64 + bj * 32 + l31];
    bo[bj] = bias[ocol0 + wc * 64 + bj * 32 + l31];
  }
  float qv[2][16];
  #pragma unroll
  for (int ai = 0; ai < 2; ++ai)
    #pragma unroll
    for (int g = 0; g < 4; ++g) {
      float4 q4 = *(const float4*)(qs + srow0 + wr * 64 + ai * 32 + 4 * h + 8 * g);
      qv[ai][4*g+0] = q4.x; qv[ai][4*g+1] = q4.y;
      qv[ai][4*g+2] = q4.z; qv[ai][4*g+3] = q4.w;
    }

  // Swizzled 16B-chunk read offsets: chunk c = ks*2 + h;
  // physical chunk = c ^ (row&7) ^ ((row>>3)&3).
  int aoff[4][2], boff[4][2];
  #pragma unroll
  for (int ks = 0; ks < 4; ++ks) {
    #pragma unroll
    for (int f = 0; f < 2; ++f) {
      const int rowA = wr * 64 + f * 32 + l31;
      const int rowB = wc * 64 + f * 32 + l31;
      const int c    = ks * 2 + h;
      const int fA   = (rowA & 7) ^ ((rowA >> 3) & 3);
      const int fB   = (rowB & 7) ^ ((rowB >> 3) & 3);
      aoff[ks][f] = rowA * 128 + ((c ^ fA) * 16);
      boff[ks][f] = rowB * 128 + ((c ^ fB) * 16);
    }
  }

  const int rloc0 = wid * 32 + (lane >> 3);
  const int clA   = (lane & 7);

  auto stage8 = [&](int ktB, int buf) {
    #pragma unroll
    for (int q = 0; q < 4; ++q) {
      const int rl = rloc0 + q * 8;
      const int cl = clA ^ (rl & 7) ^ ((rl >> 3) & 3);
      gload16(A8 + (size_t)(srow0 + rl) * INTD + ktB + cl * 16,
              &lds[buf][0][wid * 32 + q * 8][0]);
      gload16(W8 + (size_t)(ocol0 + rl) * INTD + ktB + cl * 16,
              &lds[buf][1][wid * 32 + q * 8][0]);
    }
  };
  auto stagefp = [&](int ktB, int buf) {
    #pragma unroll
    for (int q = 0; q < 4; ++q) {
      const int rl = rloc0 + q * 8;
      const int cl = clA ^ (rl & 7) ^ ((rl >> 3) & 3);
      gload16(Afp + (size_t)(srow0 + rl) * 512 + ktB + cl * 16,
              &lds[buf][0][wid * 32 + q * 8][0]);
      gload16(Wfp + (size_t)(ocol0 + rl) * 512 + ktB + cl * 16,
              &lds[buf][1][wid * 32 + q * 8][0]);
    }
  };

  i32x16 iacc[2][2];
  #pragma unroll
  for (int i = 0; i < 2; ++i)
    #pragma unroll
    for (int j = 0; j < 2; ++j)
      iacc[i][j] = (i32x16)(0);

  stage8(0, 0);
  int cur = 0;
  constexpr int NT8 = INTD / 128;   // 30
  for (int t = 0; t < NT8; ++t) {
    __syncthreads();
    if (t + 1 < NT8) stage8((t + 1) * 128, cur ^ 1);
    else             stagefp(0, cur ^ 1);
    const char* Al = &lds[cur][0][0][0];
    const char* Bl = &lds[cur][1][0][0];
    #pragma unroll
    for (int ks = 0; ks < 4; ++ks) {
      i32x4 af[2], bv[2];
      #pragma unroll
      for (int f = 0; f < 2; ++f) {
        af[f] = *(const i32x4*)(Al + aoff[ks][f]);
        bv[f] = *(const i32x4*)(Bl + boff[ks][f]);
      }
      #pragma unroll
      for (int i = 0; i < 2; ++i)
        #pragma unroll
        for (int j = 0; j < 2; ++j)
          iacc[i][j] = __builtin_amdgcn_mfma_i32_32x32x32_i8(
              af[i], bv[j], iacc[i][j], 0, 0, 0);
    }
    cur ^= 1;
  }

  // Convert i32 -> f32 with per-row/col scales (overlaps fp tile-0 in flight).
  f32x16 facc[2][2];
  #pragma unroll
  for (int i = 0; i < 2; ++i)
    #pragma unroll
    for (int j = 0; j < 2; ++j)
      #pragma unroll
      for (int r = 0; r < 16; ++r)
        facc[i][j][r] = (float)iacc[i][j][r] * wo[j] * qv[i][r];

  constexpr int NTF = (FPD * 2) / 128;   // 4
  for (int t = 0; t < NTF; ++t) {
    __syncthreads();
    if (t + 1 < NTF) stagefp((t + 1) * 128, cur ^ 1);
    const char* Al = &lds[cur][0][0][0];
    const char* Bl = &lds[cur][1][0][0];
    #pragma unroll
    for (int ks = 0; ks < 4; ++ks) {
      bf16x8 af[2], bv[2];
      #pragma unroll
      for (int f = 0; f < 2; ++f) {
        af[f] = *(const bf16x8*)(Al + aoff[ks][f]);
        bv[f] = *(const bf16x8*)(Bl + boff[ks][f]);
      }
      #pragma unroll
      for (int i = 0; i < 2; ++i)
        #pragma unroll
        for (int j = 0; j < 2; ++j)
          facc[i][j] = __builtin_amdgcn_mfma_f32_32x32x16_bf16(
              af[i], bv[j], facc[i][j], 0, 0, 0);
    }
    cur ^= 1;
  }

  // Epilogue: 32x32 C/D layout col=l31, row=(reg&3)+8*(reg>>2)+4*h.
  #pragma unroll
  for (int j = 0; j < 2; ++j) {
    const int o = ocol0 + wc * 64 + j * 32 + l31;
    #pragma unroll
    for (int i = 0; i < 2; ++i) {
      const int sbase = srow0 + wr * 64 + i * 32 + 4 * h;
      #pragma unroll
      for (int g = 0; g < 4; ++g)
        #pragma unroll
        for (int r = 0; r < 4; ++r)
          out[(size_t)(sbase + 8 * g + r) * ODIM + o] = facc[i][j][4*g+r] + bo[j];
    }
  }
}

// ---------------------------------------------------------------------------
extern "C" void kernel_launch(void* const* d_in, const int* in_sizes, int n_in,
                              void* d_out, int out_size, void* d_ws, size_t ws_size,
                              hipStream_t stream) {
  const float* x    = (const float*)d_in[0];
  const float* iw   = (const float*)d_in[1];
  const float* fw   = (const float*)d_in[2];
  const float* wsc  = (const float*)d_in[3];
  const float* bias = (const float*)d_in[4];
  const int* int_idx = (const int*)d_in[5];
  const int* fp_idx  = (const int*)d_in[6];
  float* out = (float*)d_out;

  char* ws = (char*)d_ws;
  char* A8  = ws;                                   // 2048*3840  = 7.86 MB
  char* W8  = A8 + (size_t)SDIM * INTD;             // 4096*3840  = 15.7 MB
  char* Afp = W8 + (size_t)ODIM * INTD;             // 2048*256*2 = 1.0 MB
  char* Wfp = Afp + (size_t)SDIM * FPD * 2;         // 4096*256*2 = 2.1 MB
  float* qs = (float*)(Wfp + (size_t)ODIM * FPD * 2);

  prep_kernel<<<SDIM + ODIM, 256, 0, stream>>>(x, iw, fw, int_idx, fp_idx,
                                               (unsigned*)A8, (unsigned short*)Afp,
                                               (unsigned*)W8, (unsigned short*)Wfp, qs);
  gemm_kernel<<<512, 256, 0, stream>>>(A8, W8, Afp, Wfp, qs, wsc, bias, out);
}